// Round 11
// baseline (339.627 us; speedup 1.0000x reference)
//
#include <hip/hip_runtime.h>

#define IN_F   512
#define OUT_F  512
#define GRID_N 8
#define BATCH  4096
#define KDIM   (IN_F * 9)        // 4608
#define SPLITK 8
#define KCHUNK (KDIM / SPLITK)   // 576
#define BK     64
#define NSTEPS (KCHUNK / BK)     // 9
#define NTILES ((BATCH / 128) * (OUT_F / 128))   // 128 output tiles

typedef __fp16 half8  __attribute__((ext_vector_type(8)));
typedef float  f32x4  __attribute__((ext_vector_type(4)));
typedef float  f32x16 __attribute__((ext_vector_type(16)));

__device__ __forceinline__ void gload16(const void* gsrc, void* ldst) {
  __builtin_amdgcn_global_load_lds(
      (__attribute__((address_space(1))) void*)(void*)gsrc,
      (__attribute__((address_space(3))) void*)ldst, 16, 0, 0);
}

// ------- prep: feature expansion Phi[b][g*512+i] + weight pack -------------
__global__ void prep_kernel(const float* __restrict__ x, const float* __restrict__ grid,
                            const float* __restrict__ sw, const float* __restrict__ ba,
                            __fp16* __restrict__ A, __fp16* __restrict__ W) {
  const int bid = blockIdx.x;
  if (bid < (BATCH * IN_F) / 256) {            // ---- feat path ----
    const int idx = bid * 256 + threadIdx.x;   // b*512 + i
    const float xn = tanhf(x[idx]);
    const int b = idx >> 9;
    const int i = idx & (IN_F - 1);
    __fp16* arow = A + (size_t)b * KDIM + i;
#pragma unroll
    for (int g = 0; g < GRID_N; ++g) {
      const float d  = fabsf(xn - grid[g]);
      const float dd = d * d;
      const float inner = 1.0f - 6.0f * dd + 6.0f * dd * d;
      const float om = 1.0f - d;
      const float outer = 2.0f * om * om * om;
      const float bas = (d < 0.5f) ? inner : ((d < 1.0f) ? outer : 0.0f);
      arow[g * IN_F] = (__fp16)bas;
    }
    arow[8 * IN_F] = (__fp16)xn;
  } else {                                     // ---- weight path ----
    const int idx = (bid - (BATCH * IN_F) / 256) * 256 + threadIdx.x;  // o*512+i
    const float* swp = sw + (size_t)idx * GRID_N;
    __fp16* wrow = W + (size_t)(idx >> 9) * KDIM + (idx & (IN_F - 1));
#pragma unroll
    for (int g = 0; g < GRID_N; ++g) wrow[g * IN_F] = (__fp16)swp[g];
    wrow[8 * IN_F] = (__fp16)(0.1f * ba[idx]);
  }
}

// ------- split-K GEMM + chained reduce -------------------------------------
// r4 skeleton: 128x128 tile, 4 waves of 64x64, BK=64, single LDS buffer,
// 2-barrier loop, XOR swizzle source-side + read-side. z = wgid&7 -> XCD
// shares K-chunk slices in L2. NEW: (a) MFMA 32x32x16 (higher FLOP/cyc,
// same LDS volume); (b) last-arriving z-partner reduces the 8 fp16 P
// slices into f32 out (atomic counter + device fences), no reduce kernel.
__global__ __launch_bounds__(256, 3) void gemm_kernel(const __fp16* __restrict__ A,
                                                      const __fp16* __restrict__ W,
                                                      __fp16* __restrict__ P,
                                                      int* __restrict__ cnt,
                                                      float* __restrict__ out) {
  __shared__ __align__(16) __fp16 As[128 * BK];
  __shared__ __align__(16) __fp16 Bs[128 * BK];
  __shared__ int s_old;
  const int tid  = threadIdx.x;
  const int lane = tid & 63;
  const int wv   = tid >> 6;
  const int wm   = wv >> 1;
  const int wn   = wv & 1;
  const int wg   = blockIdx.x;
  const int z    = wg & 7;          // XCD id == K-chunk id (wgid%8 round-robin)
  const int t    = wg >> 3;         // output tile id, 0..127
  const int m0   = (t >> 2) * 128;
  const int n0   = (t & 3) * 128;
  const int kbase = z * KCHUNK;

  // staging: issue tile t4 = wv*4+j covers halves [t4*512, +512):
  // rows r = t4*8 + lane/8, global col-chunk pre-swizzled by ^(r&7),
  // LDS dest linear (global_load_lds writes base + lane*16).
  const __fp16* Ag[4];
  const __fp16* Wg[4];
  __fp16* lA[4];
  __fp16* lB[4];
#pragma unroll
  for (int j = 0; j < 4; ++j) {
    const int t4 = wv * 4 + j;
    const int r = t4 * 8 + (lane >> 3);
    const int cs = ((lane & 7) ^ (r & 7)) * 8;
    Ag[j] = A + (size_t)(m0 + r) * KDIM + kbase + cs;
    Wg[j] = W + (size_t)(n0 + r) * KDIM + kbase + cs;
    lA[j] = &As[t4 * 512];
    lB[j] = &Bs[t4 * 512];
  }

  const int cl = lane & 31;            // MFMA 32x32 row/col within tile
  const int hi = lane >> 5;            // k-group
  const int xr = cl & 7;               // read-side row-XOR (rows are +0 mod 8)

  f32x16 acc[2][2] = {};

  for (int kt = 0; kt < NSTEPS; ++kt) {
#pragma unroll
    for (int j = 0; j < 4; ++j) {
      gload16(Ag[j], lA[j]);
      gload16(Wg[j], lB[j]);
      Ag[j] += BK; Wg[j] += BK;
    }
    __syncthreads();                   // drains vmcnt: tile resident

    half8 a[4][2], b[4][2];
#pragma unroll
    for (int kp = 0; kp < 4; ++kp) {   // 4 k-phases of 16
#pragma unroll
      for (int mt = 0; mt < 2; ++mt) {
        const int row = wm * 64 + mt * 32 + cl;
        const int ch = (kp * 2 + hi) ^ xr;
        a[kp][mt] = *(const half8*)&As[row * BK + ch * 8];
      }
#pragma unroll
      for (int nt = 0; nt < 2; ++nt) {
        const int row = wn * 64 + nt * 32 + cl;
        const int ch = (kp * 2 + hi) ^ xr;
        b[kp][nt] = *(const half8*)&Bs[row * BK + ch * 8];
      }
    }
#pragma unroll
    for (int kp = 0; kp < 4; ++kp)
#pragma unroll
      for (int mt = 0; mt < 2; ++mt)
#pragma unroll
        for (int nt = 0; nt < 2; ++nt)
          acc[mt][nt] = __builtin_amdgcn_mfma_f32_32x32x16_f16(
              a[kp][mt], b[kp][nt], acc[mt][nt], 0, 0, 0);
    __syncthreads();
  }

  // -------- write fp16 partial slice --------
  __fp16* Pp = P + (size_t)z * (BATCH * OUT_F);
#pragma unroll
  for (int mt = 0; mt < 2; ++mt) {
#pragma unroll
    for (int nt = 0; nt < 2; ++nt) {
      const int col = n0 + wn * 64 + nt * 32 + cl;
#pragma unroll
      for (int rg = 0; rg < 16; ++rg) {
        // C/D 32x32: row = (reg&3) + 8*(reg>>2) + 4*(lane>>5), col = lane&31
        const int row = m0 + wm * 64 + mt * 32 + (rg & 3) + 8 * (rg >> 2) + 4 * hi;
        Pp[(size_t)row * OUT_F + col] = (__fp16)acc[mt][nt][rg];
      }
    }
  }

  // -------- chained reduce: last z-partner sums the 8 slices --------
  __threadfence();                       // release: P-writes visible device-wide
  if (tid == 0) s_old = atomicAdd(&cnt[t], 1);
  __syncthreads();
  if (s_old == SPLITK - 1) {
    __threadfence();                     // acquire: partners' P-writes
    const int BO = BATCH * OUT_F;
#pragma unroll
    for (int j = 0; j < 8; ++j) {
      const int u = tid * 8 + j;         // 0..2047 half8-units of the 128x128 tile
      const int row = u >> 4;
      const int c8 = u & 15;
      const size_t off = (size_t)(m0 + row) * OUT_F + n0 + c8 * 8;
      float s[8] = {};
#pragma unroll
      for (int zz = 0; zz < SPLITK; ++zz) {
        const half8 v = *(const half8*)&P[(size_t)zz * BO + off];
#pragma unroll
        for (int e = 0; e < 8; ++e) s[e] += (float)v[e];
      }
      f32x4 lo = {s[0], s[1], s[2], s[3]};
      f32x4 hi4 = {s[4], s[5], s[6], s[7]};
      *(f32x4*)&out[off]     = lo;
      *(f32x4*)&out[off + 4] = hi4;
    }
  }
}

extern "C" void kernel_launch(void* const* d_in, const int* in_sizes, int n_in,
                              void* d_out, int out_size, void* d_ws, size_t ws_size,
                              hipStream_t stream) {
  const float* x  = (const float*)d_in[0];
  const float* sw = (const float*)d_in[1];
  const float* ba = (const float*)d_in[2];
  const float* gp = (const float*)d_in[3];
  float* out = (float*)d_out;

  char* ws = (char*)d_ws;
  const size_t A_BYTES = (size_t)BATCH * KDIM * 2;   // 37,748,736
  const size_t W_BYTES = (size_t)OUT_F * KDIM * 2;   //  4,718,592
  const size_t P_BYTES = (size_t)SPLITK * BATCH * OUT_F * 2;  // 33,554,432
  __fp16* A = (__fp16*)ws;
  __fp16* W = (__fp16*)(ws + A_BYTES);
  __fp16* P = (__fp16*)(ws + A_BYTES + W_BYTES);
  int*  cnt = (int*)(ws + A_BYTES + W_BYTES + P_BYTES);

  hipMemsetAsync(cnt, 0, NTILES * sizeof(int), stream);
  const int FEAT_BLKS = (BATCH * IN_F) / 256;        // 8192
  const int WT_BLKS   = (OUT_F * IN_F) / 256;        // 1024
  prep_kernel<<<FEAT_BLKS + WT_BLKS, 256, 0, stream>>>(x, gp, sw, ba, A, W);
  gemm_kernel<<<NTILES * SPLITK, 256, 0, stream>>>(A, W, P, cnt, out);
}

// Round 12
// 111.136 us; speedup vs baseline: 3.0560x; 3.0560x over previous
//
#include <hip/hip_runtime.h>

#define IN_F   512
#define OUT_F  512
#define GRID_N 8
#define BATCH  4096
#define KDIM   (IN_F * 9)        // 4608
#define SPLITK 8
#define KCHUNK (KDIM / SPLITK)   // 576
#define BK     64
#define NSTEPS (KCHUNK / BK)     // 9

typedef __fp16 half8  __attribute__((ext_vector_type(8)));
typedef float  f32x4  __attribute__((ext_vector_type(4)));
typedef float  f32x16 __attribute__((ext_vector_type(16)));

__device__ __forceinline__ void gload16(const void* gsrc, void* ldst) {
  __builtin_amdgcn_global_load_lds(
      (__attribute__((address_space(1))) void*)(void*)gsrc,
      (__attribute__((address_space(3))) void*)ldst, 16, 0, 0);
}

// ------- prep: feature expansion Phi[b][g*512+i] + weight pack -------------
__global__ void prep_kernel(const float* __restrict__ x, const float* __restrict__ grid,
                            const float* __restrict__ sw, const float* __restrict__ ba,
                            __fp16* __restrict__ A, __fp16* __restrict__ W) {
  const int bid = blockIdx.x;
  if (bid < (BATCH * IN_F) / 256) {            // ---- feat path ----
    const int idx = bid * 256 + threadIdx.x;   // b*512 + i
    const float xn = tanhf(x[idx]);
    const int b = idx >> 9;
    const int i = idx & (IN_F - 1);
    __fp16* arow = A + (size_t)b * KDIM + i;
#pragma unroll
    for (int g = 0; g < GRID_N; ++g) {
      const float d  = fabsf(xn - grid[g]);
      const float dd = d * d;
      const float inner = 1.0f - 6.0f * dd + 6.0f * dd * d;
      const float om = 1.0f - d;
      const float outer = 2.0f * om * om * om;
      const float bas = (d < 0.5f) ? inner : ((d < 1.0f) ? outer : 0.0f);
      arow[g * IN_F] = (__fp16)bas;
    }
    arow[8 * IN_F] = (__fp16)xn;
  } else {                                     // ---- weight path ----
    const int idx = (bid - (BATCH * IN_F) / 256) * 256 + threadIdx.x;  // o*512+i
    const float* swp = sw + (size_t)idx * GRID_N;
    __fp16* wrow = W + (size_t)(idx >> 9) * KDIM + (idx & (IN_F - 1));
#pragma unroll
    for (int g = 0; g < GRID_N; ++g) wrow[g * IN_F] = (__fp16)swp[g];
    wrow[8 * IN_F] = (__fp16)(0.1f * ba[idx]);
  }
}

// ------- split-K GEMM: P[z][m][n] = Phi_chunk . Wp_chunk^T (fp16 partials) -
// r4 skeleton verbatim (best measured: 106.9): 128x128 tile, 4 waves of
// 64x64, BK=64, single LDS buffer, 2-barrier loop, XOR swizzle source-side
// + read-side, z = wgid&7 XCD mapping, fp16 P, separate reduce kernel.
// ONLY change vs r4: MFMA 32x32x16 (higher FLOP/cyc, same LDS volume).
// NO fences/atomics: r11 measured the chained-reduce fences at ~+200us
// (L2 writeback/invalidate per block on non-coherent XCD L2s).
__global__ __launch_bounds__(256, 3) void gemm_kernel(const __fp16* __restrict__ A,
                                                      const __fp16* __restrict__ W,
                                                      __fp16* __restrict__ P) {
  __shared__ __align__(16) __fp16 As[128 * BK];
  __shared__ __align__(16) __fp16 Bs[128 * BK];
  const int tid  = threadIdx.x;
  const int lane = tid & 63;
  const int wv   = tid >> 6;
  const int wm   = wv >> 1;
  const int wn   = wv & 1;
  const int wg   = blockIdx.x;
  const int z    = wg & 7;          // XCD id == K-chunk id (wgid%8 round-robin)
  const int t    = wg >> 3;         // output tile id, 0..127
  const int m0   = (t >> 2) * 128;
  const int n0   = (t & 3) * 128;
  const int kbase = z * KCHUNK;

  // staging: issue tile t4 = wv*4+j covers halves [t4*512, +512):
  // rows r = t4*8 + lane/8, global col-chunk pre-swizzled by ^(r&7),
  // LDS dest linear (global_load_lds writes base + lane*16).
  const __fp16* Ag[4];
  const __fp16* Wg[4];
  __fp16* lA[4];
  __fp16* lB[4];
#pragma unroll
  for (int j = 0; j < 4; ++j) {
    const int t4 = wv * 4 + j;
    const int r = t4 * 8 + (lane >> 3);
    const int cs = ((lane & 7) ^ (r & 7)) * 8;
    Ag[j] = A + (size_t)(m0 + r) * KDIM + kbase + cs;
    Wg[j] = W + (size_t)(n0 + r) * KDIM + kbase + cs;
    lA[j] = &As[t4 * 512];
    lB[j] = &Bs[t4 * 512];
  }

  const int cl = lane & 31;            // MFMA 32x32 row/col within tile
  const int hi = lane >> 5;            // k-group
  const int xr = cl & 7;               // read-side row-XOR (row&7 == cl&7)

  f32x16 acc[2][2] = {};

  for (int kt = 0; kt < NSTEPS; ++kt) {
#pragma unroll
    for (int j = 0; j < 4; ++j) {
      gload16(Ag[j], lA[j]);
      gload16(Wg[j], lB[j]);
      Ag[j] += BK; Wg[j] += BK;
    }
    __syncthreads();                   // drains vmcnt: tile resident

    half8 a[4][2], b[4][2];
#pragma unroll
    for (int kp = 0; kp < 4; ++kp) {   // 4 k-phases of 16
#pragma unroll
      for (int mt = 0; mt < 2; ++mt) {
        const int row = wm * 64 + mt * 32 + cl;
        const int ch = (kp * 2 + hi) ^ xr;
        a[kp][mt] = *(const half8*)&As[row * BK + ch * 8];
      }
#pragma unroll
      for (int nt = 0; nt < 2; ++nt) {
        const int row = wn * 64 + nt * 32 + cl;
        const int ch = (kp * 2 + hi) ^ xr;
        b[kp][nt] = *(const half8*)&Bs[row * BK + ch * 8];
      }
    }
#pragma unroll
    for (int kp = 0; kp < 4; ++kp)
#pragma unroll
      for (int mt = 0; mt < 2; ++mt)
#pragma unroll
        for (int nt = 0; nt < 2; ++nt)
          acc[mt][nt] = __builtin_amdgcn_mfma_f32_32x32x16_f16(
              a[kp][mt], b[kp][nt], acc[mt][nt], 0, 0, 0);
    __syncthreads();
  }

  // C/D 32x32: row = (reg&3) + 8*(reg>>2) + 4*(lane>>5), col = lane&31
  __fp16* Pp = P + (size_t)z * (BATCH * OUT_F);
#pragma unroll
  for (int mt = 0; mt < 2; ++mt) {
#pragma unroll
    for (int nt = 0; nt < 2; ++nt) {
      const int col = n0 + wn * 64 + nt * 32 + cl;
#pragma unroll
      for (int rg = 0; rg < 16; ++rg) {
        const int row = m0 + wm * 64 + mt * 32 + (rg & 3) + 8 * (rg >> 2) + 4 * hi;
        Pp[(size_t)row * OUT_F + col] = (__fp16)acc[mt][nt][rg];
      }
    }
  }
}

// ------- reduce 8 fp16 split-K partials ------------------------------------
__global__ void reduce_kernel(const __fp16* __restrict__ P, float* __restrict__ out) {
  const int idx = blockIdx.x * 256 + threadIdx.x;   // half8 group, 0..262143
  float s[8] = {};
#pragma unroll
  for (int zz = 0; zz < SPLITK; ++zz) {
    const half8 v = *(const half8*)&P[(size_t)zz * (BATCH * OUT_F) + (size_t)idx * 8];
#pragma unroll
    for (int e = 0; e < 8; ++e) s[e] += (float)v[e];
  }
  f32x4 lo = {s[0], s[1], s[2], s[3]};
  f32x4 hi = {s[4], s[5], s[6], s[7]};
  ((f32x4*)out)[idx * 2]     = lo;
  ((f32x4*)out)[idx * 2 + 1] = hi;
}

extern "C" void kernel_launch(void* const* d_in, const int* in_sizes, int n_in,
                              void* d_out, int out_size, void* d_ws, size_t ws_size,
                              hipStream_t stream) {
  const float* x  = (const float*)d_in[0];
  const float* sw = (const float*)d_in[1];
  const float* ba = (const float*)d_in[2];
  const float* gp = (const float*)d_in[3];
  float* out = (float*)d_out;

  char* ws = (char*)d_ws;
  const size_t A_BYTES = (size_t)BATCH * KDIM * 2;   // 37,748,736
  const size_t W_BYTES = (size_t)OUT_F * KDIM * 2;   //  4,718,592
  __fp16* A = (__fp16*)ws;
  __fp16* W = (__fp16*)(ws + A_BYTES);
  __fp16* P = (__fp16*)(ws + A_BYTES + W_BYTES);     // 8 x 4 MB fp16 partials

  const int FEAT_BLKS = (BATCH * IN_F) / 256;        // 8192
  const int WT_BLKS   = (OUT_F * IN_F) / 256;        // 1024
  prep_kernel<<<FEAT_BLKS + WT_BLKS, 256, 0, stream>>>(x, gp, sw, ba, A, W);
  gemm_kernel<<<(BATCH / 128) * (OUT_F / 128) * SPLITK, 256, 0, stream>>>(A, W, P);
  reduce_kernel<<<(BATCH * OUT_F) / 8 / 256, 256, 0, stream>>>(P, out);
}

// Round 13
// 110.935 us; speedup vs baseline: 3.0615x; 1.0018x over previous
//
#include <hip/hip_runtime.h>

#define IN_F   512
#define OUT_F  512
#define GRID_N 8
#define BATCH  4096
#define KDIM   (IN_F * 9)        // 4608
#define SPLITK 8
#define KCHUNK (KDIM / SPLITK)   // 576
#define BK     64
#define NSTEPS (KCHUNK / BK)     // 9
#define BM     256
#define BN     256

typedef __fp16 half8  __attribute__((ext_vector_type(8)));
typedef float  f32x4  __attribute__((ext_vector_type(4)));

__device__ __forceinline__ void gload16(const void* gsrc, void* ldst) {
  __builtin_amdgcn_global_load_lds(
      (__attribute__((address_space(1))) void*)(void*)gsrc,
      (__attribute__((address_space(3))) void*)ldst, 16, 0, 0);
}

// ------- prep: feature expansion Phi[b][g*512+i] + weight pack -------------
__global__ void prep_kernel(const float* __restrict__ x, const float* __restrict__ grid,
                            const float* __restrict__ sw, const float* __restrict__ ba,
                            __fp16* __restrict__ A, __fp16* __restrict__ W) {
  const int bid = blockIdx.x;
  if (bid < (BATCH * IN_F) / 256) {            // ---- feat path ----
    const int idx = bid * 256 + threadIdx.x;   // b*512 + i
    const float xn = tanhf(x[idx]);
    const int b = idx >> 9;
    const int i = idx & (IN_F - 1);
    __fp16* arow = A + (size_t)b * KDIM + i;
#pragma unroll
    for (int g = 0; g < GRID_N; ++g) {
      const float d  = fabsf(xn - grid[g]);
      const float dd = d * d;
      const float inner = 1.0f - 6.0f * dd + 6.0f * dd * d;
      const float om = 1.0f - d;
      const float outer = 2.0f * om * om * om;
      const float bas = (d < 0.5f) ? inner : ((d < 1.0f) ? outer : 0.0f);
      arow[g * IN_F] = (__fp16)bas;
    }
    arow[8 * IN_F] = (__fp16)xn;
  } else {                                     // ---- weight path ----
    const int idx = (bid - (BATCH * IN_F) / 256) * 256 + threadIdx.x;  // o*512+i
    const float* swp = sw + (size_t)idx * GRID_N;
    __fp16* wrow = W + (size_t)(idx >> 9) * KDIM + (idx & (IN_F - 1));
#pragma unroll
    for (int g = 0; g < GRID_N; ++g) wrow[g * IN_F] = (__fp16)swp[g];
    wrow[8 * IN_F] = (__fp16)(0.1f * ba[idx]);
  }
}

// ------- split-K GEMM: P[z][m][n] = Phi_chunk . Wp_chunk^T (fp16 partials) -
// TRAFFIC-OPTIMIZED TILE: 256x256, 16 waves (4x4) of 64x64, 1024 threads,
// BK=64, 64KB LDS single buffer, 2-barrier loop (r4-proven), XOR swizzle
// source-side + read-side, 16x16x32 MFMA (measured better than 32x32x16).
// Stage traffic = Mt*Nt*(BM+BN)*K*2B = 151MB, half of the 128x128 variants
// (302MB) that all plateaued at ~85us GEMM. z = wg&7 -> XCD K-chunk L2 reuse.
__global__ __launch_bounds__(1024) void gemm_kernel(const __fp16* __restrict__ A,
                                                    const __fp16* __restrict__ W,
                                                    __fp16* __restrict__ P) {
  __shared__ __align__(16) __fp16 As[BM * BK];   // 32 KB
  __shared__ __align__(16) __fp16 Bs[BN * BK];   // 32 KB
  const int tid  = threadIdx.x;
  const int lane = tid & 63;
  const int fr   = lane & 15;
  const int g4   = lane >> 4;
  const int wv   = tid >> 6;        // 0..15
  const int wr   = wv >> 2;         // 0..3
  const int wc   = wv & 3;          // 0..3
  const int wg   = blockIdx.x;      // 0..255
  const int z    = wg & 7;          // XCD id == K-chunk id (wgid%8 round-robin)
  const int tile = wg >> 3;         // 0..31
  const int m0   = (tile >> 1) * BM;
  const int n0   = (tile & 1) * BN;
  const int kbase = z * KCHUNK;

  // staging: 2048 16B-chunks per operand tile; thread covers c = j*1024+tid.
  // row r = c>>3 (8 chunks/row), global col-chunk pre-swizzled by ^(r&7),
  // LDS dest linear (global_load_lds rule: base + lane*16).
  const __fp16* Ag[2];
  const __fp16* Wg[2];
  int aoff[2];
#pragma unroll
  for (int j = 0; j < 2; ++j) {
    const int c = j * 1024 + tid;
    const int r = c >> 3;
    const int cc = (c & 7) ^ (r & 7);
    Ag[j] = A + (size_t)(m0 + r) * KDIM + kbase + cc * 8;
    Wg[j] = W + (size_t)(n0 + r) * KDIM + kbase + cc * 8;
    aoff[j] = c * 8;
  }

  const int xr = fr & 7;               // read-side row-XOR (row&7 == fr&7)

  f32x4 acc[4][4] = {};

  for (int kt = 0; kt < NSTEPS; ++kt) {
#pragma unroll
    for (int j = 0; j < 2; ++j) {
      gload16(Ag[j], &As[aoff[j]]);
      gload16(Wg[j], &Bs[aoff[j]]);
      Ag[j] += BK; Wg[j] += BK;
    }
    __syncthreads();                   // drains vmcnt: tile resident

    half8 a[2][4], b[2][4];
#pragma unroll
    for (int ks = 0; ks < 2; ++ks) {
#pragma unroll
      for (int mi = 0; mi < 4; ++mi) {
        const int row = wr * 64 + mi * 16 + fr;
        const int ch = (ks * 4 + g4) ^ xr;
        a[ks][mi] = *(const half8*)&As[row * BK + ch * 8];
      }
#pragma unroll
      for (int ni = 0; ni < 4; ++ni) {
        const int row = wc * 64 + ni * 16 + fr;
        const int ch = (ks * 4 + g4) ^ xr;
        b[ks][ni] = *(const half8*)&Bs[row * BK + ch * 8];
      }
    }
#pragma unroll
    for (int ks = 0; ks < 2; ++ks)
#pragma unroll
      for (int mi = 0; mi < 4; ++mi)
#pragma unroll
        for (int ni = 0; ni < 4; ++ni)
          acc[mi][ni] = __builtin_amdgcn_mfma_f32_16x16x32_f16(
              a[ks][mi], b[ks][ni], acc[mi][ni], 0, 0, 0);
    __syncthreads();
  }

  // C/D 16x16: row = (lane>>4)*4 + reg, col = lane&15
  __fp16* Pp = P + (size_t)z * (BATCH * OUT_F);
#pragma unroll
  for (int mi = 0; mi < 4; ++mi) {
#pragma unroll
    for (int ni = 0; ni < 4; ++ni) {
      const int row = m0 + wr * 64 + mi * 16 + g4 * 4;
      const int col = n0 + wc * 64 + ni * 16 + fr;
#pragma unroll
      for (int rg = 0; rg < 4; ++rg)
        Pp[(size_t)(row + rg) * OUT_F + col] = (__fp16)acc[mi][ni][rg];
    }
  }
}

// ------- reduce 8 fp16 split-K partials ------------------------------------
__global__ void reduce_kernel(const __fp16* __restrict__ P, float* __restrict__ out) {
  const int idx = blockIdx.x * 256 + threadIdx.x;   // half8 group, 0..262143
  float s[8] = {};
#pragma unroll
  for (int zz = 0; zz < SPLITK; ++zz) {
    const half8 v = *(const half8*)&P[(size_t)zz * (BATCH * OUT_F) + (size_t)idx * 8];
#pragma unroll
    for (int e = 0; e < 8; ++e) s[e] += (float)v[e];
  }
  f32x4 lo = {s[0], s[1], s[2], s[3]};
  f32x4 hi = {s[4], s[5], s[6], s[7]};
  ((f32x4*)out)[idx * 2]     = lo;
  ((f32x4*)out)[idx * 2 + 1] = hi;
}

extern "C" void kernel_launch(void* const* d_in, const int* in_sizes, int n_in,
                              void* d_out, int out_size, void* d_ws, size_t ws_size,
                              hipStream_t stream) {
  const float* x  = (const float*)d_in[0];
  const float* sw = (const float*)d_in[1];
  const float* ba = (const float*)d_in[2];
  const float* gp = (const float*)d_in[3];
  float* out = (float*)d_out;

  char* ws = (char*)d_ws;
  const size_t A_BYTES = (size_t)BATCH * KDIM * 2;   // 37,748,736
  const size_t W_BYTES = (size_t)OUT_F * KDIM * 2;   //  4,718,592
  __fp16* A = (__fp16*)ws;
  __fp16* W = (__fp16*)(ws + A_BYTES);
  __fp16* P = (__fp16*)(ws + A_BYTES + W_BYTES);     // 8 x 4 MB fp16 partials

  const int FEAT_BLKS = (BATCH * IN_F) / 256;        // 8192
  const int WT_BLKS   = (OUT_F * IN_F) / 256;        // 1024
  prep_kernel<<<FEAT_BLKS + WT_BLKS, 256, 0, stream>>>(x, gp, sw, ba, A, W);
  gemm_kernel<<<(BATCH / BM) * (OUT_F / BN) * SPLITK, 1024, 0, stream>>>(A, W, P);
  reduce_kernel<<<(BATCH * OUT_F) / 8 / 256, 256, 0, stream>>>(P, out);
}